// Round 10
// baseline (252.640 us; speedup 1.0000x reference)
//
#include <hip/hip_runtime.h>
#include <hip/hip_fp16.h>
#include <stdint.h>

#define D_FEAT 64
#define CH 4096         // edges per chunk in hist/place
#define BKT_BITS 8      // 256 rows per bucket

// ---------------- bucket histogram per chunk ----------------
__global__ __launch_bounds__(256) void bhist_kernel(const int* __restrict__ rows,
                                                    int* __restrict__ block_hist,
                                                    int n_edges, int nb) {
    __shared__ int cnt[256];
    cnt[threadIdx.x] = 0;
    __syncthreads();
    int beg = blockIdx.x * CH;
    int end = min(beg + CH, n_edges);
    for (int i = beg + threadIdx.x; i < end; i += 256)
        atomicAdd(&cnt[rows[i] >> BKT_BITS], 1);
    __syncthreads();
    if (threadIdx.x < nb)
        block_hist[blockIdx.x * nb + threadIdx.x] = cnt[threadIdx.x];
}

// ---------------- parallel scan: per-bucket column over chunks (nchunks <= 512) ----------------
__global__ __launch_bounds__(256) void bscan1_kernel(int* __restrict__ block_hist,
                                                     int* __restrict__ btot,
                                                     int nchunks, int nb) {
    __shared__ int buf[256];
    int j = blockIdx.x;
    int t = threadIdx.x;
    int c0 = 2 * t, c1 = 2 * t + 1;
    int v0 = (c0 < nchunks) ? block_hist[(size_t)c0 * nb + j] : 0;
    int v1 = (c1 < nchunks) ? block_hist[(size_t)c1 * nb + j] : 0;
    int loc = v0 + v1;
    buf[t] = loc;
    __syncthreads();
    for (int off = 1; off < 256; off <<= 1) {
        int add = (t >= off) ? buf[t - off] : 0;
        __syncthreads();
        buf[t] += add;
        __syncthreads();
    }
    int excl = buf[t] - loc;
    if (c0 < nchunks) block_hist[(size_t)c0 * nb + j] = excl;
    if (c1 < nchunks) block_hist[(size_t)c1 * nb + j] = excl + v0;
    if (t == 255) btot[j] = buf[255];
}

__global__ __launch_bounds__(256) void bscan2_kernel(const int* __restrict__ btot,
                                                     int* __restrict__ bbase, int nb) {
    __shared__ int buf[256];
    int t = threadIdx.x;
    int v = (t < nb) ? btot[t] : 0;
    buf[t] = v;
    __syncthreads();
    for (int off = 1; off < 256; off <<= 1) {
        int add = (t >= off) ? buf[t - off] : 0;
        __syncthreads();
        buf[t] += add;
        __syncthreads();
    }
    if (t < nb) {
        bbase[t] = buf[t] - v;
        if (t == nb - 1) bbase[nb] = buf[t];
    }
}

// ---------------- place edges into bucket-contiguous mid array ----------------
__global__ __launch_bounds__(256) void bplace_kernel(const float* __restrict__ vals,
                                                     const int* __restrict__ rows,
                                                     const int* __restrict__ cols,
                                                     const int* __restrict__ block_hist,
                                                     const int* __restrict__ bbase,
                                                     uint2* __restrict__ mid,
                                                     int n_edges, int nb) {
    __shared__ int cnt[256];
    __shared__ int base[256];
    int t = threadIdx.x;
    cnt[t] = 0;
    if (t < nb) base[t] = bbase[t] + block_hist[(size_t)blockIdx.x * nb + t];
    __syncthreads();
    int beg = blockIdx.x * CH;
    int end = min(beg + CH, n_edges);
    for (int i = beg + t; i < end; i += 256) {
        int r = rows[i];
        int b = r >> BKT_BITS;
        int lrank = atomicAdd(&cnt[b], 1);
        __half hv = __float2half_rn(vals[i]);
        unsigned short vb = *reinterpret_cast<unsigned short*>(&hv);
        uint32_t packed = (uint32_t)(cols[i] & 0xFFFF) | ((uint32_t)vb << 16);
        mid[base[b] + lrank] = make_uint2(packed, (uint32_t)r);
    }
}

// ---------------- per-bucket counting sort by row + fused offs[] (no rank stash) ----------------
__global__ __launch_bounds__(256) void bsort_kernel(const uint2* __restrict__ mid,
                                                    const int* __restrict__ bbase,
                                                    uint32_t* __restrict__ edges,
                                                    int* __restrict__ offs,
                                                    int n_nodes, int nb) {
    __shared__ int cnt[256];
    __shared__ int start[256];
    __shared__ int buf[256];
    int j = blockIdx.x;
    int t = threadIdx.x;
    int lo = bbase[j];
    int hi = bbase[j + 1];
    cnt[t] = 0;
    __syncthreads();
    const uint32_t RMASK = (1u << BKT_BITS) - 1u;
    for (int i = lo + t; i < hi; i += 256)
        atomicAdd(&cnt[mid[i].y & RMASK], 1);
    __syncthreads();
    int v = cnt[t];
    buf[t] = v;
    __syncthreads();
    for (int off = 1; off < 256; off <<= 1) {
        int add = (t >= off) ? buf[t - off] : 0;
        __syncthreads();
        buf[t] += add;
        __syncthreads();
    }
    int st = buf[t] - v;
    start[t] = st;
    int rg = (j << BKT_BITS) + t;
    if (rg <= n_nodes) offs[rg] = lo + st;
    __syncthreads();
    cnt[t] = 0;
    __syncthreads();
    for (int i = lo + t; i < hi; i += 256) {
        uint2 e = mid[i];
        int r = (int)(e.y & RMASK);
        int rank = atomicAdd(&cnt[r], 1);
        edges[lo + start[r] + rank] = e.x;
    }
}

// ---------------- SpMM: one wave per row, 8 subgroups x 8 lanes, 16B/lane gathers -------

__device__ __forceinline__ float unpack_val(uint32_t u) {
    __half_raw hr;
    hr.x = (unsigned short)(u >> 16);
    return __half2float(__half(hr));
}

__device__ __forceinline__ float2 h2f(uint32_t w) {
    __half2 h = *reinterpret_cast<__half2*>(&w);
    return __half22float2(h);
}

__device__ __forceinline__ uint32_t f2h2(float a, float b) {
    __half2 h = __float22half2_rn(make_float2(a, b));
    return *reinterpret_cast<uint32_t*>(&h);
}

__device__ __forceinline__ void fma8_h(const uint4& q, float v, float* acc) {
    float2 f;
    f = h2f(q.x); acc[0] = fmaf(v, f.x, acc[0]); acc[1] = fmaf(v, f.y, acc[1]);
    f = h2f(q.y); acc[2] = fmaf(v, f.x, acc[2]); acc[3] = fmaf(v, f.y, acc[3]);
    f = h2f(q.z); acc[4] = fmaf(v, f.x, acc[4]); acc[5] = fmaf(v, f.y, acc[5]);
    f = h2f(q.w); acc[6] = fmaf(v, f.x, acc[6]); acc[7] = fmaf(v, f.y, acc[7]);
}

__device__ __forceinline__ void fma8_f(const float4& q0, const float4& q1, float v, float* acc) {
    acc[0] = fmaf(v, q0.x, acc[0]); acc[1] = fmaf(v, q0.y, acc[1]);
    acc[2] = fmaf(v, q0.z, acc[2]); acc[3] = fmaf(v, q0.w, acc[3]);
    acc[4] = fmaf(v, q1.x, acc[4]); acc[5] = fmaf(v, q1.y, acc[5]);
    acc[6] = fmaf(v, q1.z, acc[6]); acc[7] = fmaf(v, q1.w, acc[7]);
}

template <bool IN_F32, bool OUT_F32>
__global__ __launch_bounds__(256) void spmm8_kernel(const void* __restrict__ hv,
                                                    const uint32_t* __restrict__ edges,
                                                    const int* __restrict__ offs,
                                                    void* __restrict__ outv, int n_nodes) {
    int row = (int)(((long long)blockIdx.x * blockDim.x + threadIdx.x) >> 6);
    if (row >= n_nodes) return;
    int lane = threadIdx.x & 63;
    int sg = lane >> 3;     // subgroup = which edge of the 8-batch
    int fl = lane & 7;      // feature block: feats [fl*8, fl*8+8)

    int beg = offs[row], end = offs[row + 1];
    float acc[8] = {0.f, 0.f, 0.f, 0.f, 0.f, 0.f, 0.f, 0.f};

    int j0 = beg;
    // full passes: 16 edges in flight (two 8-edge groups)
    for (; j0 + 16 <= end; j0 += 16) {
        uint32_t ua = edges[j0 + sg];
        uint32_t ub = edges[j0 + 8 + sg];
        if (IN_F32) {
            const float4* hp = (const float4*)hv;
            size_t ca = (size_t)(ua & 0xFFFF) * 16 + fl * 2;
            size_t cb = (size_t)(ub & 0xFFFF) * 16 + fl * 2;
            float4 qa0 = hp[ca], qa1 = hp[ca + 1];
            float4 qb0 = hp[cb], qb1 = hp[cb + 1];
            fma8_f(qa0, qa1, unpack_val(ua), acc);
            fma8_f(qb0, qb1, unpack_val(ub), acc);
        } else {
            const uint4* hp = (const uint4*)hv;
            uint4 qa = hp[(size_t)(ua & 0xFFFF) * 8 + fl];
            uint4 qb = hp[(size_t)(ub & 0xFFFF) * 8 + fl];
            fma8_h(qa, unpack_val(ua), acc);
            fma8_h(qb, unpack_val(ub), acc);
        }
    }
    // tail: one 8-edge group at a time, subgroup-uniform masking
    for (; j0 < end; j0 += 8) {
        int j = j0 + sg;
        if (j < end) {
            uint32_t u = edges[j];
            float v = unpack_val(u);
            if (IN_F32) {
                const float4* hp = (const float4*)hv;
                size_t c = (size_t)(u & 0xFFFF) * 16 + fl * 2;
                float4 q0 = hp[c], q1 = hp[c + 1];
                fma8_f(q0, q1, v, acc);
            } else {
                const uint4* hp = (const uint4*)hv;
                uint4 q = hp[(size_t)(u & 0xFFFF) * 8 + fl];
                fma8_h(q, v, acc);
            }
        }
    }

    // reduce across the 8 subgroups (lanes fl, fl+8, ..., fl+56)
#pragma unroll
    for (int m = 8; m <= 32; m <<= 1) {
#pragma unroll
        for (int i = 0; i < 8; ++i) acc[i] += __shfl_xor(acc[i], m, 64);
    }

    // store: 8 (fp16) or 16 (f32) lanes write the 128B/256B row coalesced
    if (OUT_F32) {
        float4* op = (float4*)outv + (size_t)row * 16 + fl * 2;
        if (sg == 0) op[0] = make_float4(acc[0], acc[1], acc[2], acc[3]);
        else if (sg == 1) op[1] = make_float4(acc[4], acc[5], acc[6], acc[7]);
    } else {
        if (sg == 0) {
            uint4 o;
            o.x = f2h2(acc[0], acc[1]);
            o.y = f2h2(acc[2], acc[3]);
            o.z = f2h2(acc[4], acc[5]);
            o.w = f2h2(acc[6], acc[7]);
            ((uint4*)outv)[(size_t)row * 8 + fl] = o;
        }
    }
}

// ---------------- fallback (atomic path) ----------------

__global__ void spmm_atomic_kernel(const float* __restrict__ h,
                                   const float* __restrict__ vals,
                                   const int* __restrict__ rows,
                                   const int* __restrict__ cols,
                                   float* __restrict__ out,
                                   int n_edges) {
    long long tid = (long long)blockIdx.x * blockDim.x + threadIdx.x;
    int e = (int)(tid >> 6);
    int d = (int)(tid & 63);
    if (e >= n_edges) return;
    float m = vals[e] * h[(size_t)cols[e] * D_FEAT + d];
    atomicAdd(&out[(size_t)rows[e] * D_FEAT + d], m);
}

extern "C" void kernel_launch(void* const* d_in, const int* in_sizes, int n_in,
                              void* d_out, int out_size, void* d_ws, size_t ws_size,
                              hipStream_t stream) {
    const float* x    = (const float*)d_in[0];
    const float* vals = (const float*)d_in[1];
    const int*   rows = (const int*)d_in[2];
    const int*   cols = (const int*)d_in[3];

    int n_nodes = in_sizes[0] / D_FEAT;
    int n_edges = in_sizes[1];

    float* out = (float*)d_out;

    size_t buf_bytes_f32 = (size_t)n_nodes * D_FEAT * sizeof(float);
    size_t buf_bytes_f16 = (size_t)n_nodes * D_FEAT * sizeof(__half);

    auto align_up = [](size_t v) { return (v + 255) & ~(size_t)255; };

    int nb = (n_nodes + 255) >> BKT_BITS;
    int nchunks = (n_edges + CH - 1) / CH;

    size_t pa_b   = align_up(buf_bytes_f16);
    size_t pb_b   = align_up(buf_bytes_f16);
    size_t mid_b  = align_up((size_t)n_edges * sizeof(uint2));
    size_t region1 = pa_b + pb_b;
    if (mid_b > region1) region1 = mid_b;          // mid aliases pA/pB (dead before spmm)
    size_t edges_b = align_up((size_t)n_edges * sizeof(uint32_t));
    size_t offs_b  = align_up((size_t)(n_nodes + 1) * sizeof(int));
    size_t bh_b    = align_up((size_t)nchunks * nb * sizeof(int));
    size_t bb_b    = align_up((size_t)(nb + 1) * sizeof(int));
    size_t bt_b    = align_up(256 * sizeof(int));
    size_t need = region1 + edges_b + offs_b + bh_b + bb_b + bt_b;

    if (ws_size < need || n_nodes > 65536 || nchunks > 512) {
        float* ws = (float*)d_ws;
        float* dsts[5] = {out, ws, out, ws, out};
        long long total_threads = (long long)n_edges * D_FEAT;
        int block = 256;
        int grid = (int)((total_threads + block - 1) / block);
        const float* src = x;
        for (int s = 0; s < 5; ++s) {
            hipMemsetAsync(dsts[s], 0, buf_bytes_f32, stream);
            spmm_atomic_kernel<<<grid, block, 0, stream>>>(src, vals, rows, cols,
                                                           dsts[s], n_edges);
            src = dsts[s];
        }
        return;
    }

    char* p = (char*)d_ws;
    char* r1 = p;                        p += region1;
    uint32_t* edges      = (uint32_t*)p; p += edges_b;
    int*      offs       = (int*)p;      p += offs_b;
    int*      block_hist = (int*)p;      p += bh_b;
    int*      bbase      = (int*)p;      p += bb_b;
    int*      btot       = (int*)p;      p += bt_b;

    __half* pA = (__half*)r1;
    __half* pB = (__half*)(r1 + pa_b);
    uint2*  mid = (uint2*)r1;            // aliases pA/pB; consumed before they're written

    // ---- build row-sorted packed edge list + offs ----
    bhist_kernel<<<nchunks, 256, 0, stream>>>(rows, block_hist, n_edges, nb);
    bscan1_kernel<<<nb, 256, 0, stream>>>(block_hist, btot, nchunks, nb);
    bscan2_kernel<<<1, 256, 0, stream>>>(btot, bbase, nb);
    bplace_kernel<<<nchunks, 256, 0, stream>>>(vals, rows, cols, block_hist, bbase,
                                               mid, n_edges, nb);
    bsort_kernel<<<nb, 256, 0, stream>>>(mid, bbase, edges, offs, n_nodes, nb);

    // ---- 5 SpMM steps: x(f32) -> pA(f16) -> pB -> pA -> pB -> out(f32) ----
    {
        int rows_per_block = 4;  // 4 waves, 1 row each
        int grid = (n_nodes + rows_per_block - 1) / rows_per_block;
        spmm8_kernel<true,  false><<<grid, 256, 0, stream>>>(x,  edges, offs, pA, n_nodes);
        spmm8_kernel<false, false><<<grid, 256, 0, stream>>>(pA, edges, offs, pB, n_nodes);
        spmm8_kernel<false, false><<<grid, 256, 0, stream>>>(pB, edges, offs, pA, n_nodes);
        spmm8_kernel<false, false><<<grid, 256, 0, stream>>>(pA, edges, offs, pB, n_nodes);
        spmm8_kernel<false, true ><<<grid, 256, 0, stream>>>(pB, edges, offs, out, n_nodes);
    }
}